// Round 1
// baseline (1364.440 us; speedup 1.0000x reference)
//
#include <hip/hip_runtime.h>
#include <stdint.h>

// Problem constants (match reference)
#define T_TOK 8192
#define HID   1024
#define INTER 4096
#define NE    8
#define TOPK  2
#define CAP   2048            // min(ceil(T*K*CF/E), T) = 2048
#define EC    (NE * CAP)      // 16384 slots

// Workspace layout (bytes). Total = 436,338,688 B (~416.1 MB).
//  [0,   64MB)  WgT  bf16 (E, INTER, HID)   gate_w transposed
//  [64,  128MB) WuT  bf16 (E, INTER, HID)
//  [128, 192MB) WdT  bf16 (E, HID, INTER)   down_w transposed
//  [192, 224MB) Xe   bf16 (EC, HID)         gathered tokens
//  [224, 352MB) inter bf16 (EC, INTER)
//  [352, 416MB) pout fp32 (EC, HID)         permuted expert output
//  [416MB .. )  perm int (T,2), assign int (EC)

typedef __attribute__((ext_vector_type(8))) short bf16x8;
typedef __attribute__((ext_vector_type(4))) float f32x4;

static __device__ __forceinline__ unsigned short f2bf(float f) {
    union { float f; unsigned u; } a; a.f = f;
    unsigned r = a.u + 0x7FFFu + ((a.u >> 16) & 1u);   // round-nearest-even
    return (unsigned short)(r >> 16);
}

static __device__ __forceinline__ void gload_lds16(const unsigned short* g, unsigned short* l) {
    // async global->LDS, 16B/lane; LDS dest = wave-uniform base + lane*16
    __builtin_amdgcn_global_load_lds((__attribute__((address_space(1))) void*)(uintptr_t)g,
                                     (__attribute__((address_space(3))) void*)l, 16, 0, 0);
}

// ---------------------------------------------------------------- routing ---
// One block, 8 waves; wave e handles expert e. Exact replication of the
// reference: inclusive cumsum of the (possibly 2-valued) expert mask, capacity
// drop where position > C, 1-based slot index (0 == dropped), slot->token map.
__global__ __launch_bounds__(512) void route_kernel(const int* __restrict__ eidx,
                                                    int* __restrict__ perm,
                                                    int* __restrict__ assign) {
    int tid = threadIdx.x;
    for (int i = tid; i < EC; i += 512) assign[i] = 0;   // empty slot -> token 0
    __syncthreads();
    int e = tid >> 6;          // wave index == expert
    int lane = tid & 63;
    const int TPL = T_TOK / 64;                          // 128 tokens per lane
    int t0 = lane * TPL;
    // pass 1: local counts
    int cnt = 0;
    for (int t = t0; t < t0 + TPL; ++t) {
        int e0 = eidx[t * 2], e1 = eidx[t * 2 + 1];
        cnt += (e0 == e) + (e1 == e);
    }
    // exclusive scan across 64 lanes
    int incl = cnt;
    #pragma unroll
    for (int off = 1; off < 64; off <<= 1) {
        int n = __shfl_up(incl, off, 64);
        if (lane >= off) incl += n;
    }
    int run = incl - cnt;      // tokens before this lane's range
    // pass 2: positions, capacity, slot assignment
    for (int t = t0; t < t0 + TPL; ++t) {
        int e0 = eidx[t * 2], e1 = eidx[t * 2 + 1];
        int c = (e0 == e) + (e1 == e);
        if (c) {
            run += c;
            int pos = run;                       // inclusive (1-based)
            bool keep = (pos <= CAP);
            int pi = keep ? (pos + e * CAP) : 0; // 1-based flat slot
            if (e0 == e) perm[t * 2]     = pi;
            if (e1 == e) perm[t * 2 + 1] = pi;
            if (keep) assign[pi - 1] = t;        // 0-based token id
        }
    }
}

// --------------------------------------------------- transpose + fp32->bf16 --
// in: (E, R, Cc) fp32 row-major  ->  out: (E, Cc, R) bf16 row-major
__global__ __launch_bounds__(256) void transpose_cvt(const float* __restrict__ in,
                                                     unsigned short* __restrict__ out,
                                                     int R, int Cc) {
    __shared__ unsigned short tile[64][65];
    int e = blockIdx.z;
    const float* inp = in + (size_t)e * R * Cc;
    unsigned short* outp = out + (size_t)e * R * Cc;
    int c0 = blockIdx.x * 64, r0 = blockIdx.y * 64;
    int x = threadIdx.x, y = threadIdx.y;
    #pragma unroll
    for (int ry = y; ry < 64; ry += 4)
        tile[ry][x] = f2bf(inp[(size_t)(r0 + ry) * Cc + c0 + x]);
    __syncthreads();
    #pragma unroll
    for (int oy = y; oy < 64; oy += 4)
        outp[(size_t)(c0 + oy) * R + r0 + x] = tile[x][oy];
}

// ------------------------------------------------------- gather + cvt tokens -
__global__ __launch_bounds__(256) void gather_cvt(const float* __restrict__ hs,
                                                  const int* __restrict__ assign,
                                                  unsigned short* __restrict__ xe) {
    int s = blockIdx.x;
    int tok = assign[s];
    const float* src = hs + (size_t)tok * HID;
    unsigned short* dst = xe + (size_t)s * HID;
    int h = threadIdx.x * 4;
    float4 v = *(const float4*)(src + h);
    ushort4 o;
    o.x = f2bf(v.x); o.y = f2bf(v.y); o.z = f2bf(v.z); o.w = f2bf(v.w);
    *(ushort4*)(dst + h) = o;
}

// --------------------------------------------- fused gate+up GEMM, SiLU*mul --
// Per expert: inter = silu(Xe @ Wg) * (Xe @ Wu).  A (M,K) and BT (N,K) both
// K-contiguous bf16; 128x128 tile, BK=32, 4 waves in 2x2, 16x16x32 MFMA.
__global__ __launch_bounds__(256) void gateup_gemm(const unsigned short* __restrict__ Xe,
                                                   const unsigned short* __restrict__ WgT,
                                                   const unsigned short* __restrict__ WuT,
                                                   unsigned short* __restrict__ interO) {
    const int K = HID;   // 1024
    __shared__ unsigned short lA[128 * 32];
    __shared__ unsigned short lBg[128 * 32];
    __shared__ unsigned short lBu[128 * 32];

    int e = blockIdx.z;
    int m0 = blockIdx.y * 128;
    int n0 = blockIdx.x * 128;
    const unsigned short* Ab = Xe  + ((size_t)e * CAP   + m0) * K;
    const unsigned short* Bg = WgT + ((size_t)e * INTER + n0) * K;
    const unsigned short* Bu = WuT + ((size_t)e * INTER + n0) * K;

    int tid = threadIdx.x;
    int lane = tid & 63;
    int wv = tid >> 6;
    // staging: 8 segments of 16 rows per 128-row tile; wave wv owns segs {2wv,2wv+1}
    int srow = (wv * 2) * 16 + (lane >> 2);
    int scol = (lane & 3) * 8;
    const unsigned short* a0  = Ab + (size_t)srow * K + scol;
    const unsigned short* a1  = a0 + (size_t)16 * K;
    const unsigned short* bg0 = Bg + (size_t)srow * K + scol;
    const unsigned short* bg1 = bg0 + (size_t)16 * K;
    const unsigned short* bu0 = Bu + (size_t)srow * K + scol;
    const unsigned short* bu1 = bu0 + (size_t)16 * K;
    unsigned short* lA0  = &lA [(wv * 2) * 512];
    unsigned short* lA1  = lA0 + 512;
    unsigned short* lBg0 = &lBg[(wv * 2) * 512];
    unsigned short* lBg1 = lBg0 + 512;
    unsigned short* lBu0 = &lBu[(wv * 2) * 512];
    unsigned short* lBu1 = lBu0 + 512;

    int lm = lane & 15;
    int kq = (lane >> 4) * 8;
    int wmB = (wv >> 1) * 64;
    int wnB = (wv & 1) * 64;

    f32x4 zero = {0.f, 0.f, 0.f, 0.f};
    f32x4 accG[4][4], accU[4][4];
    #pragma unroll
    for (int i = 0; i < 4; i++)
        #pragma unroll
        for (int j = 0; j < 4; j++) { accG[i][j] = zero; accU[i][j] = zero; }

    for (int kk = 0; kk < K / 32; ++kk) {
        int ko = kk * 32;
        gload_lds16(a0  + ko, lA0);
        gload_lds16(a1  + ko, lA1);
        gload_lds16(bg0 + ko, lBg0);
        gload_lds16(bg1 + ko, lBg1);
        gload_lds16(bu0 + ko, lBu0);
        gload_lds16(bu1 + ko, lBu1);
        __syncthreads();
        bf16x8 aF[4];
        #pragma unroll
        for (int mi = 0; mi < 4; mi++)
            aF[mi] = *(const bf16x8*)&lA[(wmB + mi * 16 + lm) * 32 + kq];
        #pragma unroll
        for (int ni = 0; ni < 4; ni++) {
            bf16x8 g = *(const bf16x8*)&lBg[(wnB + ni * 16 + lm) * 32 + kq];
            bf16x8 u = *(const bf16x8*)&lBu[(wnB + ni * 16 + lm) * 32 + kq];
            #pragma unroll
            for (int mi = 0; mi < 4; mi++) {
                accG[mi][ni] = __builtin_amdgcn_mfma_f32_16x16x32_bf16(aF[mi], g, accG[mi][ni], 0, 0, 0);
                accU[mi][ni] = __builtin_amdgcn_mfma_f32_16x16x32_bf16(aF[mi], u, accU[mi][ni], 0, 0, 0);
            }
        }
        __syncthreads();
    }

    // epilogue: silu(gate)*up -> bf16, C/D layout col=lane&15, row=(lane>>4)*4+r
    unsigned short* Op = interO + ((size_t)e * CAP + m0) * INTER + n0;
    #pragma unroll
    for (int mi = 0; mi < 4; mi++)
        #pragma unroll
        for (int ni = 0; ni < 4; ni++)
            #pragma unroll
            for (int r = 0; r < 4; r++) {
                int row = wmB + mi * 16 + (lane >> 4) * 4 + r;
                int col = wnB + ni * 16 + lm;
                float g = accG[mi][ni][r];
                float u = accU[mi][ni][r];
                float s = g * (1.f / (1.f + __expf(-g))) * u;
                Op[(size_t)row * INTER + col] = f2bf(s);
            }
}

// ------------------------------------------------------------- down GEMM ----
__global__ __launch_bounds__(256) void down_gemm(const unsigned short* __restrict__ interB,
                                                 const unsigned short* __restrict__ WdT,
                                                 float* __restrict__ pout) {
    const int K = INTER;  // 4096
    __shared__ unsigned short lA[128 * 32];
    __shared__ unsigned short lB[128 * 32];

    int e = blockIdx.z;
    int m0 = blockIdx.y * 128;
    int n0 = blockIdx.x * 128;
    const unsigned short* Ab = interB + ((size_t)e * CAP + m0) * K;
    const unsigned short* Bb = WdT    + ((size_t)e * HID + n0) * K;

    int tid = threadIdx.x;
    int lane = tid & 63;
    int wv = tid >> 6;
    int srow = (wv * 2) * 16 + (lane >> 2);
    int scol = (lane & 3) * 8;
    const unsigned short* a0 = Ab + (size_t)srow * K + scol;
    const unsigned short* a1 = a0 + (size_t)16 * K;
    const unsigned short* b0 = Bb + (size_t)srow * K + scol;
    const unsigned short* b1 = b0 + (size_t)16 * K;
    unsigned short* lA0 = &lA[(wv * 2) * 512];
    unsigned short* lA1 = lA0 + 512;
    unsigned short* lB0 = &lB[(wv * 2) * 512];
    unsigned short* lB1 = lB0 + 512;

    int lm = lane & 15;
    int kq = (lane >> 4) * 8;
    int wmB = (wv >> 1) * 64;
    int wnB = (wv & 1) * 64;

    f32x4 zero = {0.f, 0.f, 0.f, 0.f};
    f32x4 acc[4][4];
    #pragma unroll
    for (int i = 0; i < 4; i++)
        #pragma unroll
        for (int j = 0; j < 4; j++) acc[i][j] = zero;

    for (int kk = 0; kk < K / 32; ++kk) {
        int ko = kk * 32;
        gload_lds16(a0 + ko, lA0);
        gload_lds16(a1 + ko, lA1);
        gload_lds16(b0 + ko, lB0);
        gload_lds16(b1 + ko, lB1);
        __syncthreads();
        bf16x8 aF[4];
        #pragma unroll
        for (int mi = 0; mi < 4; mi++)
            aF[mi] = *(const bf16x8*)&lA[(wmB + mi * 16 + lm) * 32 + kq];
        #pragma unroll
        for (int ni = 0; ni < 4; ni++) {
            bf16x8 b = *(const bf16x8*)&lB[(wnB + ni * 16 + lm) * 32 + kq];
            #pragma unroll
            for (int mi = 0; mi < 4; mi++)
                acc[mi][ni] = __builtin_amdgcn_mfma_f32_16x16x32_bf16(aF[mi], b, acc[mi][ni], 0, 0, 0);
        }
        __syncthreads();
    }

    float* Op = pout + ((size_t)e * CAP + m0) * HID + n0;
    #pragma unroll
    for (int mi = 0; mi < 4; mi++)
        #pragma unroll
        for (int ni = 0; ni < 4; ni++)
            #pragma unroll
            for (int r = 0; r < 4; r++) {
                int row = wmB + mi * 16 + (lane >> 4) * 4 + r;
                int col = wnB + ni * 16 + lm;
                Op[(size_t)row * HID + col] = acc[mi][ni][r];
            }
}

// --------------------------------------------------------------- combine ----
__global__ __launch_bounds__(256) void combine_kernel(const float* __restrict__ aff,
                                                      const int* __restrict__ eidx,
                                                      const int* __restrict__ perm,
                                                      const float* __restrict__ pout,
                                                      float* __restrict__ out) {
    int t = blockIdx.x;
    int e0 = eidx[t * 2], e1 = eidx[t * 2 + 1];
    int p0 = perm[t * 2], p1 = perm[t * 2 + 1];
    bool k0 = p0 > 0, k1 = p1 > 0;
    float a0 = aff[t * NE + e0], a1 = aff[t * NE + e1];
    // denom counts each distinct kept expert once (duplicate top-k -> once)
    float denom = (k0 ? fabsf(a0) : 0.f) + ((e1 != e0 && k1) ? fabsf(a1) : 0.f);
    denom = fmaxf(denom, 1e-12f);
    float w0 = k0 ? a0 / denom : 0.f;
    float w1 = k1 ? a1 / denom : 0.f;
    int s0 = k0 ? p0 - 1 : 0;
    int s1 = k1 ? p1 - 1 : 0;
    int h = threadIdx.x * 4;
    float4 v0 = *(const float4*)(pout + (size_t)s0 * HID + h);
    float4 v1 = *(const float4*)(pout + (size_t)s1 * HID + h);
    float4 o;
    o.x = w0 * v0.x + w1 * v1.x;
    o.y = w0 * v0.y + w1 * v1.y;
    o.z = w0 * v0.z + w1 * v1.z;
    o.w = w0 * v0.w + w1 * v1.w;
    *(float4*)(out + (size_t)t * HID + h) = o;
}

// ----------------------------------------------------------------- launch ---
extern "C" void kernel_launch(void* const* d_in, const int* in_sizes, int n_in,
                              void* d_out, int out_size, void* d_ws, size_t ws_size,
                              hipStream_t stream) {
    const float* hs   = (const float*)d_in[0];   // (T, HID)
    const float* aff  = (const float*)d_in[1];   // (T, NE)
    const float* gw   = (const float*)d_in[2];   // (NE, HID, INTER)
    const float* uw   = (const float*)d_in[3];   // (NE, HID, INTER)
    const float* dw   = (const float*)d_in[4];   // (NE, INTER, HID)
    const int*   eidx = (const int*)d_in[5];     // (T, TOPK)
    float* out = (float*)d_out;

    char* ws = (char*)d_ws;
    unsigned short* WgT    = (unsigned short*)(ws);
    unsigned short* WuT    = (unsigned short*)(ws + ((size_t)64  << 20));
    unsigned short* WdT    = (unsigned short*)(ws + ((size_t)128 << 20));
    unsigned short* Xe     = (unsigned short*)(ws + ((size_t)192 << 20));
    unsigned short* interB = (unsigned short*)(ws + ((size_t)224 << 20));
    float*          pout   = (float*)         (ws + ((size_t)352 << 20));
    int*            perm   = (int*)           (ws + ((size_t)416 << 20));
    int*            assign = perm + (T_TOK * TOPK);

    route_kernel<<<1, 512, 0, stream>>>(eidx, perm, assign);
    transpose_cvt<<<dim3(INTER / 64, HID / 64, NE), dim3(64, 4), 0, stream>>>(gw, WgT, HID, INTER);
    transpose_cvt<<<dim3(INTER / 64, HID / 64, NE), dim3(64, 4), 0, stream>>>(uw, WuT, HID, INTER);
    transpose_cvt<<<dim3(HID / 64, INTER / 64, NE), dim3(64, 4), 0, stream>>>(dw, WdT, INTER, HID);
    gather_cvt<<<EC, 256, 0, stream>>>(hs, assign, Xe);
    gateup_gemm<<<dim3(INTER / 128, CAP / 128, NE), 256, 0, stream>>>(Xe, WgT, WuT, interB);
    down_gemm<<<dim3(HID / 128, CAP / 128, NE), 256, 0, stream>>>(interB, WdT, pout);
    combine_kernel<<<T_TOK, 256, 0, stream>>>(aff, eidx, perm, pout, out);
}

// Round 2
// 1168.310 us; speedup vs baseline: 1.1679x; 1.1679x over previous
//
#include <hip/hip_runtime.h>
#include <stdint.h>

// Problem constants (match reference)
#define T_TOK 8192
#define HID   1024
#define INTER 4096
#define NE    8
#define TOPK  2
#define CAP   2048            // min(ceil(T*K*CF/E), T) = 2048
#define EC    (NE * CAP)      // 16384 slots

// Workspace layout (bytes). Total = 436,338,688 B (~416.1 MB).
//  [0,   64MB)  WgT  bf16 (E, INTER, HID)   gate_w transposed
//  [64,  128MB) WuT  bf16 (E, INTER, HID)
//  [128, 192MB) WdT  bf16 (E, HID, INTER)   down_w transposed
//  [192, 224MB) Xe   bf16 (EC, HID)         gathered tokens
//  [224, 352MB) interB bf16 (EC, INTER)     up result, then silu(g)*u in place
//  [352, 416MB) pout fp32 (EC, HID)         permuted expert output
//  [416MB .. )  perm int (T,2), assign int (EC)

typedef __attribute__((ext_vector_type(8))) short bf16x8;
typedef __attribute__((ext_vector_type(4))) float f32x4;

static __device__ __forceinline__ unsigned short f2bf(float f) {
    union { float f; unsigned u; } a; a.f = f;
    unsigned r = a.u + 0x7FFFu + ((a.u >> 16) & 1u);   // round-nearest-even
    return (unsigned short)(r >> 16);
}
static __device__ __forceinline__ float bf2f(unsigned short b) {
    union { unsigned u; float f; } a; a.u = ((unsigned)b) << 16;
    return a.f;
}

static __device__ __forceinline__ void gload_lds16(const unsigned short* g, unsigned short* l) {
    // async global->LDS, 16B/lane; LDS dest = wave-uniform base + lane*16
    __builtin_amdgcn_global_load_lds((__attribute__((address_space(1))) void*)(uintptr_t)g,
                                     (__attribute__((address_space(3))) void*)l, 16, 0, 0);
}

// ---------------------------------------------------------------- routing ---
// One block, 8 waves; wave e handles expert e. Exact replication of the
// reference: inclusive cumsum of the (possibly 2-valued) expert mask, capacity
// drop where position > C, 1-based slot index (0 == dropped), slot->token map.
__global__ __launch_bounds__(512) void route_kernel(const int* __restrict__ eidx,
                                                    int* __restrict__ perm,
                                                    int* __restrict__ assign) {
    int tid = threadIdx.x;
    for (int i = tid; i < EC; i += 512) assign[i] = 0;   // empty slot -> token 0
    __syncthreads();
    int e = tid >> 6;          // wave index == expert
    int lane = tid & 63;
    const int TPL = T_TOK / 64;                          // 128 tokens per lane
    int t0 = lane * TPL;
    // pass 1: local counts
    int cnt = 0;
    for (int t = t0; t < t0 + TPL; ++t) {
        int e0 = eidx[t * 2], e1 = eidx[t * 2 + 1];
        cnt += (e0 == e) + (e1 == e);
    }
    // exclusive scan across 64 lanes
    int incl = cnt;
    #pragma unroll
    for (int off = 1; off < 64; off <<= 1) {
        int n = __shfl_up(incl, off, 64);
        if (lane >= off) incl += n;
    }
    int run = incl - cnt;      // tokens before this lane's range
    // pass 2: positions, capacity, slot assignment
    for (int t = t0; t < t0 + TPL; ++t) {
        int e0 = eidx[t * 2], e1 = eidx[t * 2 + 1];
        int c = (e0 == e) + (e1 == e);
        if (c) {
            run += c;
            int pos = run;                       // inclusive (1-based)
            bool keep = (pos <= CAP);
            int pi = keep ? (pos + e * CAP) : 0; // 1-based flat slot
            if (e0 == e) perm[t * 2]     = pi;
            if (e1 == e) perm[t * 2 + 1] = pi;
            if (keep) assign[pi - 1] = t;        // 0-based token id
        }
    }
}

// --------------------------------------------------- transpose + fp32->bf16 --
// in: (E, R, Cc) fp32 row-major  ->  out: (E, Cc, R) bf16 row-major
// 64x64 tile, 256 threads; float4 loads, ushort4 LDS writes + global stores.
__global__ __launch_bounds__(256) void transpose_cvt(const float* __restrict__ in,
                                                     unsigned short* __restrict__ out,
                                                     int R, int Cc) {
    __shared__ unsigned short tile[64][68];   // row stride 136 B (8B-aligned)
    int e = blockIdx.z;
    const float* inp = in + (size_t)e * R * Cc;
    unsigned short* outp = out + (size_t)e * R * Cc;
    int c0 = blockIdx.x * 64, r0 = blockIdx.y * 64;
    int t = threadIdx.x;
    int x = t & 15;            // quad-column index (4 elems each)
    int ry = t >> 4;           // 0..15
    #pragma unroll
    for (int j = 0; j < 4; ++j) {
        int row = ry + 16 * j;
        float4 v = *(const float4*)(inp + (size_t)(r0 + row) * Cc + c0 + 4 * x);
        ushort4 o;
        o.x = f2bf(v.x); o.y = f2bf(v.y); o.z = f2bf(v.z); o.w = f2bf(v.w);
        *(ushort4*)&tile[row][4 * x] = o;
    }
    __syncthreads();
    #pragma unroll
    for (int j = 0; j < 4; ++j) {
        int oc = ry + 16 * j;  // output row == original column
        ushort4 o;
        o.x = tile[4 * x + 0][oc];
        o.y = tile[4 * x + 1][oc];
        o.z = tile[4 * x + 2][oc];
        o.w = tile[4 * x + 3][oc];
        *(ushort4*)(outp + (size_t)(c0 + oc) * R + r0 + 4 * x) = o;
    }
}

// ------------------------------------------------------- gather + cvt tokens -
__global__ __launch_bounds__(256) void gather_cvt(const float* __restrict__ hs,
                                                  const int* __restrict__ assign,
                                                  unsigned short* __restrict__ xe) {
    int s = blockIdx.x;
    int tok = assign[s];
    const float* src = hs + (size_t)tok * HID;
    unsigned short* dst = xe + (size_t)s * HID;
    int h = threadIdx.x * 4;
    float4 v = *(const float4*)(src + h);
    ushort4 o;
    o.x = f2bf(v.x); o.y = f2bf(v.y); o.z = f2bf(v.z); o.w = f2bf(v.w);
    *(ushort4*)(dst + h) = o;
}

// ------------------------------------------------------------ GEMM common ---
// m97-verified structure: 128x128 tile, BK=32, 4 waves 2x2, 16x16x32 bf16 MFMA,
// global_load_lds width=16 staging, single 4x4 f32x4 accumulator per wave.
// EPI: 0 = store bf16 C, 1 = store fp32 C, 2 = read U at C, store bf16 silu(C)*U
template <int EPI>
static __device__ __forceinline__ void gemm_core(const unsigned short* __restrict__ Ab,
                                                 const unsigned short* __restrict__ Bb,
                                                 void* __restrict__ Op_v, int K, int ldc) {
    __shared__ unsigned short lA[128 * 32];
    __shared__ unsigned short lB[128 * 32];

    int tid = threadIdx.x;
    int lane = tid & 63;
    int wv = tid >> 6;
    // staging: 8 segments of 16 rows per 128-row tile; wave wv owns segs {2wv,2wv+1}
    int srow = (wv * 2) * 16 + (lane >> 2);
    int scol = (lane & 3) * 8;
    const unsigned short* a0 = Ab + (size_t)srow * K + scol;
    const unsigned short* a1 = a0 + (size_t)16 * K;
    const unsigned short* b0 = Bb + (size_t)srow * K + scol;
    const unsigned short* b1 = b0 + (size_t)16 * K;
    unsigned short* lA0 = &lA[(wv * 2) * 512];
    unsigned short* lA1 = lA0 + 512;
    unsigned short* lB0 = &lB[(wv * 2) * 512];
    unsigned short* lB1 = lB0 + 512;

    int lm = lane & 15;
    int kq = (lane >> 4) * 8;
    int wmB = (wv >> 1) * 64;
    int wnB = (wv & 1) * 64;

    f32x4 zero = {0.f, 0.f, 0.f, 0.f};
    f32x4 acc[4][4];
    #pragma unroll
    for (int i = 0; i < 4; i++)
        #pragma unroll
        for (int j = 0; j < 4; j++) acc[i][j] = zero;

    for (int kk = 0; kk < K / 32; ++kk) {
        int ko = kk * 32;
        gload_lds16(a0 + ko, lA0);
        gload_lds16(a1 + ko, lA1);
        gload_lds16(b0 + ko, lB0);
        gload_lds16(b1 + ko, lB1);
        __syncthreads();
        bf16x8 aF[4];
        #pragma unroll
        for (int mi = 0; mi < 4; mi++)
            aF[mi] = *(const bf16x8*)&lA[(wmB + mi * 16 + lm) * 32 + kq];
        #pragma unroll
        for (int ni = 0; ni < 4; ni++) {
            bf16x8 b = *(const bf16x8*)&lB[(wnB + ni * 16 + lm) * 32 + kq];
            #pragma unroll
            for (int mi = 0; mi < 4; mi++)
                acc[mi][ni] = __builtin_amdgcn_mfma_f32_16x16x32_bf16(aF[mi], b, acc[mi][ni], 0, 0, 0);
        }
        __syncthreads();
    }

    // epilogue: C/D layout col=lane&15, row=(lane>>4)*4+r
    #pragma unroll
    for (int mi = 0; mi < 4; mi++)
        #pragma unroll
        for (int ni = 0; ni < 4; ni++)
            #pragma unroll
            for (int r = 0; r < 4; r++) {
                int row = wmB + mi * 16 + (lane >> 4) * 4 + r;
                int col = wnB + ni * 16 + lm;
                size_t idx = (size_t)row * ldc + col;
                float v = acc[mi][ni][r];
                if (EPI == 0) {
                    ((unsigned short*)Op_v)[idx] = f2bf(v);
                } else if (EPI == 1) {
                    ((float*)Op_v)[idx] = v;
                } else {
                    unsigned short* Op = (unsigned short*)Op_v;
                    float u = bf2f(Op[idx]);
                    float s = v * (1.f / (1.f + __expf(-v))) * u;
                    Op[idx] = f2bf(s);
                }
            }
}

// up: U = Xe @ Wu  -> interB (bf16)
__global__ __launch_bounds__(256) void up_gemm(const unsigned short* __restrict__ Xe,
                                               const unsigned short* __restrict__ WuT,
                                               unsigned short* __restrict__ interB) {
    int e = blockIdx.z, m0 = blockIdx.y * 128, n0 = blockIdx.x * 128;
    const unsigned short* Ab = Xe  + ((size_t)e * CAP   + m0) * HID;
    const unsigned short* Bb = WuT + ((size_t)e * INTER + n0) * HID;
    unsigned short* Op = interB + ((size_t)e * CAP + m0) * INTER + n0;
    gemm_core<0>(Ab, Bb, Op, HID, INTER);
}

// gate: G = Xe @ Wg ; interB = silu(G) * interB   (in-place, tile-local RMW)
__global__ __launch_bounds__(256) void gate_gemm(const unsigned short* __restrict__ Xe,
                                                 const unsigned short* __restrict__ WgT,
                                                 unsigned short* __restrict__ interB) {
    int e = blockIdx.z, m0 = blockIdx.y * 128, n0 = blockIdx.x * 128;
    const unsigned short* Ab = Xe  + ((size_t)e * CAP   + m0) * HID;
    const unsigned short* Bb = WgT + ((size_t)e * INTER + n0) * HID;
    unsigned short* Op = interB + ((size_t)e * CAP + m0) * INTER + n0;
    gemm_core<2>(Ab, Bb, Op, HID, INTER);
}

// down: pout = interB @ Wd  (fp32 out)
__global__ __launch_bounds__(256) void down_gemm(const unsigned short* __restrict__ interB,
                                                 const unsigned short* __restrict__ WdT,
                                                 float* __restrict__ pout) {
    int e = blockIdx.z, m0 = blockIdx.y * 128, n0 = blockIdx.x * 128;
    const unsigned short* Ab = interB + ((size_t)e * CAP + m0) * INTER;
    const unsigned short* Bb = WdT    + ((size_t)e * HID + n0) * INTER;
    float* Op = pout + ((size_t)e * CAP + m0) * HID + n0;
    gemm_core<1>(Ab, Bb, Op, INTER, HID);
}

// --------------------------------------------------------------- combine ----
__global__ __launch_bounds__(256) void combine_kernel(const float* __restrict__ aff,
                                                      const int* __restrict__ eidx,
                                                      const int* __restrict__ perm,
                                                      const float* __restrict__ pout,
                                                      float* __restrict__ out) {
    int t = blockIdx.x;
    int e0 = eidx[t * 2], e1 = eidx[t * 2 + 1];
    int p0 = perm[t * 2], p1 = perm[t * 2 + 1];
    bool k0 = p0 > 0, k1 = p1 > 0;
    float a0 = aff[t * NE + e0], a1 = aff[t * NE + e1];
    // denom counts each distinct kept expert once (duplicate top-k -> once)
    float denom = (k0 ? fabsf(a0) : 0.f) + ((e1 != e0 && k1) ? fabsf(a1) : 0.f);
    denom = fmaxf(denom, 1e-12f);
    float w0 = k0 ? a0 / denom : 0.f;
    float w1 = k1 ? a1 / denom : 0.f;
    int s0 = k0 ? p0 - 1 : 0;
    int s1 = k1 ? p1 - 1 : 0;
    int h = threadIdx.x * 4;
    float4 v0 = *(const float4*)(pout + (size_t)s0 * HID + h);
    float4 v1 = *(const float4*)(pout + (size_t)s1 * HID + h);
    float4 o;
    o.x = w0 * v0.x + w1 * v1.x;
    o.y = w0 * v0.y + w1 * v1.y;
    o.z = w0 * v0.z + w1 * v1.z;
    o.w = w0 * v0.w + w1 * v1.w;
    *(float4*)(out + (size_t)t * HID + h) = o;
}

// ----------------------------------------------------------------- launch ---
extern "C" void kernel_launch(void* const* d_in, const int* in_sizes, int n_in,
                              void* d_out, int out_size, void* d_ws, size_t ws_size,
                              hipStream_t stream) {
    const float* hs   = (const float*)d_in[0];   // (T, HID)
    const float* aff  = (const float*)d_in[1];   // (T, NE)
    const float* gw   = (const float*)d_in[2];   // (NE, HID, INTER)
    const float* uw   = (const float*)d_in[3];   // (NE, HID, INTER)
    const float* dw   = (const float*)d_in[4];   // (NE, INTER, HID)
    const int*   eidx = (const int*)d_in[5];     // (T, TOPK)
    float* out = (float*)d_out;

    char* ws = (char*)d_ws;
    unsigned short* WgT    = (unsigned short*)(ws);
    unsigned short* WuT    = (unsigned short*)(ws + ((size_t)64  << 20));
    unsigned short* WdT    = (unsigned short*)(ws + ((size_t)128 << 20));
    unsigned short* Xe     = (unsigned short*)(ws + ((size_t)192 << 20));
    unsigned short* interB = (unsigned short*)(ws + ((size_t)224 << 20));
    float*          pout   = (float*)         (ws + ((size_t)352 << 20));
    int*            perm   = (int*)           (ws + ((size_t)416 << 20));
    int*            assign = perm + (T_TOK * TOPK);

    route_kernel<<<1, 512, 0, stream>>>(eidx, perm, assign);
    transpose_cvt<<<dim3(INTER / 64, HID / 64, NE), 256, 0, stream>>>(uw, WuT, HID, INTER);
    gather_cvt<<<EC, 256, 0, stream>>>(hs, assign, Xe);
    up_gemm<<<dim3(INTER / 128, CAP / 128, NE), 256, 0, stream>>>(Xe, WuT, interB);
    transpose_cvt<<<dim3(INTER / 64, HID / 64, NE), 256, 0, stream>>>(gw, WgT, HID, INTER);
    gate_gemm<<<dim3(INTER / 128, CAP / 128, NE), 256, 0, stream>>>(Xe, WgT, interB);
    transpose_cvt<<<dim3(HID / 64, INTER / 64, NE), 256, 0, stream>>>(dw, WdT, INTER, HID);
    down_gemm<<<dim3(HID / 128, CAP / 128, NE), 256, 0, stream>>>(interB, WdT, pout);
    combine_kernel<<<T_TOK, 256, 0, stream>>>(aff, eidx, perm, pout, out);
}

// Round 3
// 1145.098 us; speedup vs baseline: 1.1915x; 1.0203x over previous
//
#include <hip/hip_runtime.h>
#include <stdint.h>

// Problem constants (match reference)
#define T_TOK 8192
#define HID   1024
#define INTER 4096
#define NE    8
#define TOPK  2
#define CAP   2048            // min(ceil(T*K*CF/E), T) = 2048
#define EC    (NE * CAP)      // 16384 slots

// Workspace layout (bytes).
//  [0,   64MB)  WgT  bf16 (E, INTER, HID)   gate_w transposed
//  [64,  128MB) WuT  bf16 (E, INTER, HID)
//  [128, 192MB) WdT  bf16 (E, HID, INTER)   down_w transposed
//  [192, 224MB) Xe   bf16 (EC, HID)         gathered tokens
//  [224, 352MB) interB bf16 (EC, INTER)     silu(g)*u
//  [352, 384MB) pout bf16 (EC, HID)         permuted expert output
//  [416MB .. )  perm int (T,2), assign int (EC)

typedef __attribute__((ext_vector_type(8))) short bf16x8;
typedef __attribute__((ext_vector_type(4))) float f32x4;

static __device__ __forceinline__ unsigned short f2bf(float f) {
    union { float f; unsigned u; } a; a.f = f;
    unsigned r = a.u + 0x7FFFu + ((a.u >> 16) & 1u);   // round-nearest-even
    return (unsigned short)(r >> 16);
}
static __device__ __forceinline__ float bf2f(unsigned short b) {
    union { unsigned u; float f; } a; a.u = ((unsigned)b) << 16;
    return a.f;
}

static __device__ __forceinline__ void gload_lds16(const unsigned short* g, unsigned short* l) {
    // async global->LDS, 16B/lane; LDS dest = wave-uniform base + lane*16
    __builtin_amdgcn_global_load_lds((__attribute__((address_space(1))) void*)(uintptr_t)g,
                                     (__attribute__((address_space(3))) void*)l, 16, 0, 0);
}

// ---------------------------------------------------------------- routing ---
__global__ __launch_bounds__(512) void route_kernel(const int* __restrict__ eidx,
                                                    int* __restrict__ perm,
                                                    int* __restrict__ assign) {
    int tid = threadIdx.x;
    for (int i = tid; i < EC; i += 512) assign[i] = 0;   // empty slot -> token 0
    __syncthreads();
    int e = tid >> 6;          // wave index == expert
    int lane = tid & 63;
    const int TPL = T_TOK / 64;                          // 128 tokens per lane
    int t0 = lane * TPL;
    int cnt = 0;
    for (int t = t0; t < t0 + TPL; ++t) {
        int e0 = eidx[t * 2], e1 = eidx[t * 2 + 1];
        cnt += (e0 == e) + (e1 == e);
    }
    int incl = cnt;
    #pragma unroll
    for (int off = 1; off < 64; off <<= 1) {
        int n = __shfl_up(incl, off, 64);
        if (lane >= off) incl += n;
    }
    int run = incl - cnt;
    for (int t = t0; t < t0 + TPL; ++t) {
        int e0 = eidx[t * 2], e1 = eidx[t * 2 + 1];
        int c = (e0 == e) + (e1 == e);
        if (c) {
            run += c;
            int pos = run;                       // inclusive (1-based)
            bool keep = (pos <= CAP);
            int pi = keep ? (pos + e * CAP) : 0;
            if (e0 == e) perm[t * 2]     = pi;
            if (e1 == e) perm[t * 2 + 1] = pi;
            if (keep) assign[pi - 1] = t;
        }
    }
}

// --------------------------------------------------- transpose + fp32->bf16 --
__global__ __launch_bounds__(256) void transpose_cvt(const float* __restrict__ in,
                                                     unsigned short* __restrict__ out,
                                                     int R, int Cc) {
    __shared__ unsigned short tile[64][68];
    int e = blockIdx.z;
    const float* inp = in + (size_t)e * R * Cc;
    unsigned short* outp = out + (size_t)e * R * Cc;
    int c0 = blockIdx.x * 64, r0 = blockIdx.y * 64;
    int t = threadIdx.x;
    int x = t & 15;
    int ry = t >> 4;
    #pragma unroll
    for (int j = 0; j < 4; ++j) {
        int row = ry + 16 * j;
        float4 v = *(const float4*)(inp + (size_t)(r0 + row) * Cc + c0 + 4 * x);
        ushort4 o;
        o.x = f2bf(v.x); o.y = f2bf(v.y); o.z = f2bf(v.z); o.w = f2bf(v.w);
        *(ushort4*)&tile[row][4 * x] = o;
    }
    __syncthreads();
    #pragma unroll
    for (int j = 0; j < 4; ++j) {
        int oc = ry + 16 * j;
        ushort4 o;
        o.x = tile[4 * x + 0][oc];
        o.y = tile[4 * x + 1][oc];
        o.z = tile[4 * x + 2][oc];
        o.w = tile[4 * x + 3][oc];
        *(ushort4*)(outp + (size_t)(c0 + oc) * R + r0 + 4 * x) = o;
    }
}

// ------------------------------------------------------- gather + cvt tokens -
__global__ __launch_bounds__(256) void gather_cvt(const float* __restrict__ hs,
                                                  const int* __restrict__ assign,
                                                  unsigned short* __restrict__ xe) {
    int s = blockIdx.x;
    int tok = assign[s];
    const float* src = hs + (size_t)tok * HID;
    unsigned short* dst = xe + (size_t)s * HID;
    int h = threadIdx.x * 4;
    float4 v = *(const float4*)(src + h);
    ushort4 o;
    o.x = f2bf(v.x); o.y = f2bf(v.y); o.z = f2bf(v.z); o.w = f2bf(v.w);
    *(ushort4*)(dst + h) = o;
}

// ------------------------------------------------------------ GEMM K-loop ---
// m97 structure: 128x128 tile, BK=32, 4 waves 2x2, 16x16x32 bf16 MFMA,
// global_load_lds width=16 staging.
static __device__ __forceinline__ void kloop(const unsigned short* a0, const unsigned short* a1,
                                             const unsigned short* b0, const unsigned short* b1,
                                             unsigned short* lA, unsigned short* lB,
                                             unsigned short* lA0, unsigned short* lA1,
                                             unsigned short* lB0, unsigned short* lB1,
                                             int K, int wmB, int wnB, int lm, int kq,
                                             f32x4 acc[4][4]) {
    for (int kk = 0; kk < K / 32; ++kk) {
        int ko = kk * 32;
        gload_lds16(a0 + ko, lA0);
        gload_lds16(a1 + ko, lA1);
        gload_lds16(b0 + ko, lB0);
        gload_lds16(b1 + ko, lB1);
        __syncthreads();
        bf16x8 aF[4];
        #pragma unroll
        for (int mi = 0; mi < 4; mi++)
            aF[mi] = *(const bf16x8*)&lA[(wmB + mi * 16 + lm) * 32 + kq];
        #pragma unroll
        for (int ni = 0; ni < 4; ni++) {
            bf16x8 b = *(const bf16x8*)&lB[(wnB + ni * 16 + lm) * 32 + kq];
            #pragma unroll
            for (int mi = 0; mi < 4; mi++)
                acc[mi][ni] = __builtin_amdgcn_mfma_f32_16x16x32_bf16(aF[mi], b, acc[mi][ni], 0, 0, 0);
        }
        __syncthreads();
    }
}

#define LDB_B 136   // bounce-tile leading dim (elems): 272B rows -> 16B aligned, bank-spread

// -------------------------------------------- fused gate+up GEMM + SiLU*mul --
// Two sequential K-loops over the same A-tile: U-pass (stash packed bf16 in
// VGPRs), G-pass, then silu(G)*U -> LDS bounce -> vectorized bf16 stores.
__global__ __launch_bounds__(256) void gateup_gemm(const unsigned short* __restrict__ Xe,
                                                   const unsigned short* __restrict__ WgT,
                                                   const unsigned short* __restrict__ WuT,
                                                   unsigned short* __restrict__ interB) {
    const int K = HID;
    __shared__ unsigned short smem[128 * LDB_B];     // 34,816 B
    unsigned short* lA = smem;                        // [0, 4096) elems
    unsigned short* lB = smem + 4096;                 // [4096, 8192)

    int e = blockIdx.z, m0 = blockIdx.y * 128, n0 = blockIdx.x * 128;
    const unsigned short* Ab = Xe  + ((size_t)e * CAP   + m0) * K;
    const unsigned short* Bg = WgT + ((size_t)e * INTER + n0) * K;
    const unsigned short* Bu = WuT + ((size_t)e * INTER + n0) * K;

    int tid = threadIdx.x, lane = tid & 63, wv = tid >> 6;
    int srow = wv * 32 + (lane >> 2);
    int scol = (lane & 3) * 8;
    size_t soff = (size_t)srow * K + scol;
    const unsigned short* a0  = Ab + soff;
    const unsigned short* a1  = a0 + (size_t)16 * K;
    const unsigned short* bu0 = Bu + soff;
    const unsigned short* bu1 = bu0 + (size_t)16 * K;
    const unsigned short* bg0 = Bg + soff;
    const unsigned short* bg1 = bg0 + (size_t)16 * K;
    unsigned short* lA0 = &lA[wv * 1024];
    unsigned short* lA1 = lA0 + 512;
    unsigned short* lB0 = &lB[wv * 1024];
    unsigned short* lB1 = lB0 + 512;

    int lm = lane & 15;
    int kq = (lane >> 4) * 8;
    int rq = (lane >> 4) * 4;
    int wmB = (wv >> 1) * 64;
    int wnB = (wv & 1) * 64;

    f32x4 zero = {0.f, 0.f, 0.f, 0.f};
    f32x4 acc[4][4];
    #pragma unroll
    for (int i = 0; i < 4; i++)
        #pragma unroll
        for (int j = 0; j < 4; j++) acc[i][j] = zero;

    // pass 1: U = Xe @ Wu
    kloop(a0, a1, bu0, bu1, lA, lB, lA0, lA1, lB0, lB1, K, wmB, wnB, lm, kq, acc);

    unsigned uSt[32];   // packed bf16 pairs of U
    #pragma unroll
    for (int mi = 0; mi < 4; mi++)
        #pragma unroll
        for (int ni = 0; ni < 4; ni++)
            #pragma unroll
            for (int h = 0; h < 2; h++)
                uSt[(mi * 4 + ni) * 2 + h] =
                    (unsigned)f2bf(acc[mi][ni][2 * h]) |
                    ((unsigned)f2bf(acc[mi][ni][2 * h + 1]) << 16);

    #pragma unroll
    for (int i = 0; i < 4; i++)
        #pragma unroll
        for (int j = 0; j < 4; j++) acc[i][j] = zero;

    // pass 2: G = Xe @ Wg
    kloop(a0, a1, bg0, bg1, lA, lB, lA0, lA1, lB0, lB1, K, wmB, wnB, lm, kq, acc);

    // epilogue: silu(G)*U -> bounce tile -> vector stores
    #pragma unroll
    for (int mi = 0; mi < 4; mi++)
        #pragma unroll
        for (int ni = 0; ni < 4; ni++)
            #pragma unroll
            for (int r = 0; r < 4; r++) {
                int row = wmB + mi * 16 + rq + r;
                int col = wnB + ni * 16 + lm;
                float g = acc[mi][ni][r];
                unsigned up = uSt[(mi * 4 + ni) * 2 + (r >> 1)];
                float u = bf2f((unsigned short)((r & 1) ? (up >> 16) : (up & 0xffff)));
                float s = g / (1.f + __expf(-g)) * u;
                smem[row * LDB_B + col] = f2bf(s);
            }
    __syncthreads();
    unsigned short* Op = interB + ((size_t)e * CAP + m0) * INTER + n0;
    int rr = tid >> 4;
    int cc = (tid & 15) * 8;
    #pragma unroll
    for (int j = 0; j < 8; ++j) {
        int row = rr + 16 * j;
        bf16x8 v = *(const bf16x8*)&smem[row * LDB_B + cc];
        *(bf16x8*)(Op + (size_t)row * INTER + cc) = v;
    }
}

// ------------------------------------------------------------- down GEMM ----
// pout = interB @ Wd, bf16 out via bounce tile.
__global__ __launch_bounds__(256) void down_gemm(const unsigned short* __restrict__ interB,
                                                 const unsigned short* __restrict__ WdT,
                                                 unsigned short* __restrict__ pout) {
    const int K = INTER;
    __shared__ unsigned short smem[128 * LDB_B];
    unsigned short* lA = smem;
    unsigned short* lB = smem + 4096;

    int e = blockIdx.z, m0 = blockIdx.y * 128, n0 = blockIdx.x * 128;
    const unsigned short* Ab = interB + ((size_t)e * CAP + m0) * K;
    const unsigned short* Bb = WdT    + ((size_t)e * HID + n0) * K;

    int tid = threadIdx.x, lane = tid & 63, wv = tid >> 6;
    int srow = wv * 32 + (lane >> 2);
    int scol = (lane & 3) * 8;
    size_t soff = (size_t)srow * K + scol;
    const unsigned short* a0 = Ab + soff;
    const unsigned short* a1 = a0 + (size_t)16 * K;
    const unsigned short* b0 = Bb + soff;
    const unsigned short* b1 = b0 + (size_t)16 * K;
    unsigned short* lA0 = &lA[wv * 1024];
    unsigned short* lA1 = lA0 + 512;
    unsigned short* lB0 = &lB[wv * 1024];
    unsigned short* lB1 = lB0 + 512;

    int lm = lane & 15;
    int kq = (lane >> 4) * 8;
    int rq = (lane >> 4) * 4;
    int wmB = (wv >> 1) * 64;
    int wnB = (wv & 1) * 64;

    f32x4 zero = {0.f, 0.f, 0.f, 0.f};
    f32x4 acc[4][4];
    #pragma unroll
    for (int i = 0; i < 4; i++)
        #pragma unroll
        for (int j = 0; j < 4; j++) acc[i][j] = zero;

    kloop(a0, a1, b0, b1, lA, lB, lA0, lA1, lB0, lB1, K, wmB, wnB, lm, kq, acc);

    #pragma unroll
    for (int mi = 0; mi < 4; mi++)
        #pragma unroll
        for (int ni = 0; ni < 4; ni++)
            #pragma unroll
            for (int r = 0; r < 4; r++) {
                int row = wmB + mi * 16 + rq + r;
                int col = wnB + ni * 16 + lm;
                smem[row * LDB_B + col] = f2bf(acc[mi][ni][r]);
            }
    __syncthreads();
    unsigned short* Op = pout + ((size_t)e * CAP + m0) * HID + n0;
    int rr = tid >> 4;
    int cc = (tid & 15) * 8;
    #pragma unroll
    for (int j = 0; j < 8; ++j) {
        int row = rr + 16 * j;
        bf16x8 v = *(const bf16x8*)&smem[row * LDB_B + cc];
        *(bf16x8*)(Op + (size_t)row * HID + cc) = v;
    }
}

// --------------------------------------------------------------- combine ----
__global__ __launch_bounds__(256) void combine_kernel(const float* __restrict__ aff,
                                                      const int* __restrict__ eidx,
                                                      const int* __restrict__ perm,
                                                      const unsigned short* __restrict__ pout,
                                                      float* __restrict__ out) {
    int t = blockIdx.x;
    int e0 = eidx[t * 2], e1 = eidx[t * 2 + 1];
    int p0 = perm[t * 2], p1 = perm[t * 2 + 1];
    bool k0 = p0 > 0, k1 = p1 > 0;
    float a0 = aff[t * NE + e0], a1 = aff[t * NE + e1];
    // denom counts each distinct kept expert once (duplicate top-k -> once)
    float denom = (k0 ? fabsf(a0) : 0.f) + ((e1 != e0 && k1) ? fabsf(a1) : 0.f);
    denom = fmaxf(denom, 1e-12f);
    float w0 = k0 ? a0 / denom : 0.f;
    float w1 = k1 ? a1 / denom : 0.f;
    int s0 = k0 ? p0 - 1 : 0;
    int s1 = k1 ? p1 - 1 : 0;
    int h = threadIdx.x * 4;
    ushort4 v0 = *(const ushort4*)(pout + (size_t)s0 * HID + h);
    ushort4 v1 = *(const ushort4*)(pout + (size_t)s1 * HID + h);
    float4 o;
    o.x = w0 * bf2f(v0.x) + w1 * bf2f(v1.x);
    o.y = w0 * bf2f(v0.y) + w1 * bf2f(v1.y);
    o.z = w0 * bf2f(v0.z) + w1 * bf2f(v1.z);
    o.w = w0 * bf2f(v0.w) + w1 * bf2f(v1.w);
    *(float4*)(out + (size_t)t * HID + h) = o;
}

// ----------------------------------------------------------------- launch ---
extern "C" void kernel_launch(void* const* d_in, const int* in_sizes, int n_in,
                              void* d_out, int out_size, void* d_ws, size_t ws_size,
                              hipStream_t stream) {
    const float* hs   = (const float*)d_in[0];   // (T, HID)
    const float* aff  = (const float*)d_in[1];   // (T, NE)
    const float* gw   = (const float*)d_in[2];   // (NE, HID, INTER)
    const float* uw   = (const float*)d_in[3];   // (NE, HID, INTER)
    const float* dw   = (const float*)d_in[4];   // (NE, INTER, HID)
    const int*   eidx = (const int*)d_in[5];     // (T, TOPK)
    float* out = (float*)d_out;

    char* ws = (char*)d_ws;
    unsigned short* WgT    = (unsigned short*)(ws);
    unsigned short* WuT    = (unsigned short*)(ws + ((size_t)64  << 20));
    unsigned short* WdT    = (unsigned short*)(ws + ((size_t)128 << 20));
    unsigned short* Xe     = (unsigned short*)(ws + ((size_t)192 << 20));
    unsigned short* interB = (unsigned short*)(ws + ((size_t)224 << 20));
    unsigned short* pout   = (unsigned short*)(ws + ((size_t)352 << 20));
    int*            perm   = (int*)           (ws + ((size_t)416 << 20));
    int*            assign = perm + (T_TOK * TOPK);

    route_kernel<<<1, 512, 0, stream>>>(eidx, perm, assign);
    transpose_cvt<<<dim3(INTER / 64, HID / 64, NE), 256, 0, stream>>>(uw, WuT, HID, INTER);
    transpose_cvt<<<dim3(INTER / 64, HID / 64, NE), 256, 0, stream>>>(gw, WgT, HID, INTER);
    gather_cvt<<<EC, 256, 0, stream>>>(hs, assign, Xe);
    gateup_gemm<<<dim3(INTER / 128, CAP / 128, NE), 256, 0, stream>>>(Xe, WgT, WuT, interB);
    transpose_cvt<<<dim3(HID / 64, INTER / 64, NE), 256, 0, stream>>>(dw, WdT, INTER, HID);
    down_gemm<<<dim3(HID / 128, CAP / 128, NE), 256, 0, stream>>>(interB, WdT, pout);
    combine_kernel<<<T_TOK, 256, 0, stream>>>(aff, eidx, perm, pout, out);
}

// Round 4
// 1068.898 us; speedup vs baseline: 1.2765x; 1.0713x over previous
//
#include <hip/hip_runtime.h>
#include <stdint.h>

// Problem constants (match reference)
#define T_TOK 8192
#define HID   1024
#define INTER 4096
#define NE    8
#define TOPK  2
#define CAP   2048            // min(ceil(T*K*CF/E), T) = 2048
#define EC    (NE * CAP)      // 16384 slots

// Workspace layout (bytes).
//  [0,   64MB)  WgT  bf16 (E, INTER, HID)   gate_w transposed
//  [64,  128MB) WuT  bf16 (E, INTER, HID)
//  [128, 192MB) WdT  bf16 (E, HID, INTER)   down_w transposed
//  [192, 224MB) Xe   bf16 (EC, HID)         gathered tokens
//  [224, 352MB) interB bf16 (EC, INTER)     silu(g)*u
//  [352, 384MB) pout bf16 (EC, HID)         permuted expert output
//  [416MB .. )  perm int (T,2), assign int (EC)

typedef __attribute__((ext_vector_type(8))) short bf16x8;
typedef __attribute__((ext_vector_type(4))) float f32x4;

static __device__ __forceinline__ unsigned short f2bf(float f) {
    union { float f; unsigned u; } a; a.f = f;
    unsigned r = a.u + 0x7FFFu + ((a.u >> 16) & 1u);   // round-nearest-even
    return (unsigned short)(r >> 16);
}
static __device__ __forceinline__ float bf2f(unsigned short b) {
    union { unsigned u; float f; } a; a.u = ((unsigned)b) << 16;
    return a.f;
}

static __device__ __forceinline__ void gload_lds16(const unsigned short* g, unsigned short* l) {
    // async global->LDS, 16B/lane; LDS dest = wave-uniform base + lane*16
    __builtin_amdgcn_global_load_lds((__attribute__((address_space(1))) void*)(uintptr_t)g,
                                     (__attribute__((address_space(3))) void*)l, 16, 0, 0);
}

// ---------------------------------------------------------------- routing ---
__global__ __launch_bounds__(512) void route_kernel(const int* __restrict__ eidx,
                                                    int* __restrict__ perm,
                                                    int* __restrict__ assign) {
    int tid = threadIdx.x;
    for (int i = tid; i < EC; i += 512) assign[i] = 0;   // empty slot -> token 0
    __syncthreads();
    int e = tid >> 6;          // wave index == expert
    int lane = tid & 63;
    const int TPL = T_TOK / 64;                          // 128 tokens per lane
    int t0 = lane * TPL;
    int cnt = 0;
    for (int t = t0; t < t0 + TPL; ++t) {
        int e0 = eidx[t * 2], e1 = eidx[t * 2 + 1];
        cnt += (e0 == e) + (e1 == e);
    }
    int incl = cnt;
    #pragma unroll
    for (int off = 1; off < 64; off <<= 1) {
        int n = __shfl_up(incl, off, 64);
        if (lane >= off) incl += n;
    }
    int run = incl - cnt;
    for (int t = t0; t < t0 + TPL; ++t) {
        int e0 = eidx[t * 2], e1 = eidx[t * 2 + 1];
        int c = (e0 == e) + (e1 == e);
        if (c) {
            run += c;
            int pos = run;                       // inclusive (1-based)
            bool keep = (pos <= CAP);
            int pi = keep ? (pos + e * CAP) : 0;
            if (e0 == e) perm[t * 2]     = pi;
            if (e1 == e) perm[t * 2 + 1] = pi;
            if (keep) assign[pi - 1] = t;
        }
    }
}

// --------------------------------------------------- transpose + fp32->bf16 --
__global__ __launch_bounds__(256) void transpose_cvt(const float* __restrict__ in,
                                                     unsigned short* __restrict__ out,
                                                     int R, int Cc) {
    __shared__ unsigned short tile[64][68];
    int e = blockIdx.z;
    const float* inp = in + (size_t)e * R * Cc;
    unsigned short* outp = out + (size_t)e * R * Cc;
    int c0 = blockIdx.x * 64, r0 = blockIdx.y * 64;
    int t = threadIdx.x;
    int x = t & 15;
    int ry = t >> 4;
    #pragma unroll
    for (int j = 0; j < 4; ++j) {
        int row = ry + 16 * j;
        float4 v = *(const float4*)(inp + (size_t)(r0 + row) * Cc + c0 + 4 * x);
        ushort4 o;
        o.x = f2bf(v.x); o.y = f2bf(v.y); o.z = f2bf(v.z); o.w = f2bf(v.w);
        *(ushort4*)&tile[row][4 * x] = o;
    }
    __syncthreads();
    #pragma unroll
    for (int j = 0; j < 4; ++j) {
        int oc = ry + 16 * j;
        ushort4 o;
        o.x = tile[4 * x + 0][oc];
        o.y = tile[4 * x + 1][oc];
        o.z = tile[4 * x + 2][oc];
        o.w = tile[4 * x + 3][oc];
        *(ushort4*)(outp + (size_t)(c0 + oc) * R + r0 + 4 * x) = o;
    }
}

// ------------------------------------------------------- gather + cvt tokens -
__global__ __launch_bounds__(256) void gather_cvt(const float* __restrict__ hs,
                                                  const int* __restrict__ assign,
                                                  unsigned short* __restrict__ xe) {
    int s = blockIdx.x;
    int tok = assign[s];
    const float* src = hs + (size_t)tok * HID;
    unsigned short* dst = xe + (size_t)s * HID;
    int h = threadIdx.x * 4;
    float4 v = *(const float4*)(src + h);
    ushort4 o;
    o.x = f2bf(v.x); o.y = f2bf(v.y); o.z = f2bf(v.z); o.w = f2bf(v.w);
    *(ushort4*)(dst + h) = o;
}

#define LDB_GU 72    // gateup bounce tile leading dim (elems)
#define LDB_B 136    // down bounce tile leading dim (elems)

// -------------------------------- single-pass fused gate+up GEMM + SiLU*mul --
// Block tile 128(M) x 64(N), 4 waves at 64x32 each, dual accumulators (G,U)
// sharing one A staging. K-iters = 32. Grid: x=M (fastest, shares B slices
// across concurrently-dispatched blocks), y=N, z=expert.
__global__ __launch_bounds__(256) void gateup_gemm(const unsigned short* __restrict__ Xe,
                                                   const unsigned short* __restrict__ WgT,
                                                   const unsigned short* __restrict__ WuT,
                                                   unsigned short* __restrict__ interB) {
    const int K = HID;
    __shared__ unsigned short smem[128 * LDB_GU];   // 18432 B; staging uses first 8192 elems
    unsigned short* lA  = smem;          // 128x32 = 4096 elems
    unsigned short* lBg = smem + 4096;   // 64x32  = 2048
    unsigned short* lBu = smem + 6144;   // 64x32  = 2048

    int e = blockIdx.z, m0 = blockIdx.x * 128, n0 = blockIdx.y * 64;
    const unsigned short* Ab = Xe  + ((size_t)e * CAP   + m0) * K;
    const unsigned short* Bg = WgT + ((size_t)e * INTER + n0) * K;
    const unsigned short* Bu = WuT + ((size_t)e * INTER + n0) * K;

    int tid = threadIdx.x, lane = tid & 63, wv = tid >> 6;
    int scol = (lane & 3) * 8;
    // A: 8 segments of 16 rows; wave stages segs {2wv, 2wv+1}
    int srowA = wv * 32 + (lane >> 2);
    const unsigned short* a0 = Ab + (size_t)srowA * K + scol;
    const unsigned short* a1 = a0 + (size_t)16 * K;
    // B: 4 segments of 16 rows each; wave stages seg wv of Bg and Bu
    int srowB = wv * 16 + (lane >> 2);
    const unsigned short* bg0 = Bg + (size_t)srowB * K + scol;
    const unsigned short* bu0 = Bu + (size_t)srowB * K + scol;
    unsigned short* lA0  = &lA[wv * 1024];
    unsigned short* lA1  = lA0 + 512;
    unsigned short* lBg0 = &lBg[wv * 512];
    unsigned short* lBu0 = &lBu[wv * 512];

    int lm = lane & 15;
    int kq = (lane >> 4) * 8;
    int rq = (lane >> 4) * 4;
    int wmB = (wv >> 1) * 64;   // wave M offset within 128
    int wnB = (wv & 1) * 32;    // wave N offset within 64

    f32x4 zero = {0.f, 0.f, 0.f, 0.f};
    f32x4 accG[4][2], accU[4][2];
    #pragma unroll
    for (int i = 0; i < 4; i++)
        #pragma unroll
        for (int j = 0; j < 2; j++) { accG[i][j] = zero; accU[i][j] = zero; }

    for (int kk = 0; kk < K / 32; ++kk) {
        int ko = kk * 32;
        gload_lds16(a0  + ko, lA0);
        gload_lds16(a1  + ko, lA1);
        gload_lds16(bg0 + ko, lBg0);
        gload_lds16(bu0 + ko, lBu0);
        __syncthreads();
        bf16x8 aF[4];
        #pragma unroll
        for (int mi = 0; mi < 4; mi++)
            aF[mi] = *(const bf16x8*)&lA[(wmB + mi * 16 + lm) * 32 + kq];
        #pragma unroll
        for (int ni = 0; ni < 2; ni++) {
            bf16x8 g = *(const bf16x8*)&lBg[(wnB + ni * 16 + lm) * 32 + kq];
            bf16x8 u = *(const bf16x8*)&lBu[(wnB + ni * 16 + lm) * 32 + kq];
            #pragma unroll
            for (int mi = 0; mi < 4; mi++) {
                accG[mi][ni] = __builtin_amdgcn_mfma_f32_16x16x32_bf16(aF[mi], g, accG[mi][ni], 0, 0, 0);
                accU[mi][ni] = __builtin_amdgcn_mfma_f32_16x16x32_bf16(aF[mi], u, accU[mi][ni], 0, 0, 0);
            }
        }
        __syncthreads();
    }

    // epilogue: silu(G)*U -> bounce tile (128 x 64, ld=LDB_GU) -> vector stores
    #pragma unroll
    for (int mi = 0; mi < 4; mi++)
        #pragma unroll
        for (int ni = 0; ni < 2; ni++)
            #pragma unroll
            for (int r = 0; r < 4; r++) {
                int row = wmB + mi * 16 + rq + r;
                int col = wnB + ni * 16 + lm;
                float g = accG[mi][ni][r];
                float u = accU[mi][ni][r];
                float s = g / (1.f + __expf(-g)) * u;
                smem[row * LDB_GU + col] = f2bf(s);
            }
    __syncthreads();
    unsigned short* Op = interB + ((size_t)e * CAP + m0) * INTER + n0;
    int rr = tid >> 3;          // 0..31
    int cc = (tid & 7) * 8;     // 0..56
    #pragma unroll
    for (int j = 0; j < 4; ++j) {
        int row = rr + 32 * j;
        bf16x8 v = *(const bf16x8*)&smem[row * LDB_GU + cc];
        *(bf16x8*)(Op + (size_t)row * INTER + cc) = v;
    }
}

// ------------------------------------------------------------- down GEMM ----
// pout = interB @ Wd (bf16 out). m97 128x128 structure; grid x=M fastest.
__global__ __launch_bounds__(256) void down_gemm(const unsigned short* __restrict__ interB,
                                                 const unsigned short* __restrict__ WdT,
                                                 unsigned short* __restrict__ pout) {
    const int K = INTER;
    __shared__ unsigned short smem[128 * LDB_B];
    unsigned short* lA = smem;
    unsigned short* lB = smem + 4096;

    int e = blockIdx.z, m0 = blockIdx.x * 128, n0 = blockIdx.y * 128;
    const unsigned short* Ab = interB + ((size_t)e * CAP + m0) * K;
    const unsigned short* Bb = WdT    + ((size_t)e * HID + n0) * K;

    int tid = threadIdx.x, lane = tid & 63, wv = tid >> 6;
    int srow = wv * 32 + (lane >> 2);
    int scol = (lane & 3) * 8;
    size_t soff = (size_t)srow * K + scol;
    const unsigned short* a0 = Ab + soff;
    const unsigned short* a1 = a0 + (size_t)16 * K;
    const unsigned short* b0 = Bb + soff;
    const unsigned short* b1 = b0 + (size_t)16 * K;
    unsigned short* lA0 = &lA[wv * 1024];
    unsigned short* lA1 = lA0 + 512;
    unsigned short* lB0 = &lB[wv * 1024];
    unsigned short* lB1 = lB0 + 512;

    int lm = lane & 15;
    int kq = (lane >> 4) * 8;
    int rq = (lane >> 4) * 4;
    int wmB = (wv >> 1) * 64;
    int wnB = (wv & 1) * 64;

    f32x4 zero = {0.f, 0.f, 0.f, 0.f};
    f32x4 acc[4][4];
    #pragma unroll
    for (int i = 0; i < 4; i++)
        #pragma unroll
        for (int j = 0; j < 4; j++) acc[i][j] = zero;

    for (int kk = 0; kk < K / 32; ++kk) {
        int ko = kk * 32;
        gload_lds16(a0 + ko, lA0);
        gload_lds16(a1 + ko, lA1);
        gload_lds16(b0 + ko, lB0);
        gload_lds16(b1 + ko, lB1);
        __syncthreads();
        bf16x8 aF[4];
        #pragma unroll
        for (int mi = 0; mi < 4; mi++)
            aF[mi] = *(const bf16x8*)&lA[(wmB + mi * 16 + lm) * 32 + kq];
        #pragma unroll
        for (int ni = 0; ni < 4; ni++) {
            bf16x8 b = *(const bf16x8*)&lB[(wnB + ni * 16 + lm) * 32 + kq];
            #pragma unroll
            for (int mi = 0; mi < 4; mi++)
                acc[mi][ni] = __builtin_amdgcn_mfma_f32_16x16x32_bf16(aF[mi], b, acc[mi][ni], 0, 0, 0);
        }
        __syncthreads();
    }

    #pragma unroll
    for (int mi = 0; mi < 4; mi++)
        #pragma unroll
        for (int ni = 0; ni < 4; ni++)
            #pragma unroll
            for (int r = 0; r < 4; r++) {
                int row = wmB + mi * 16 + rq + r;
                int col = wnB + ni * 16 + lm;
                smem[row * LDB_B + col] = f2bf(acc[mi][ni][r]);
            }
    __syncthreads();
    unsigned short* Op = pout + ((size_t)e * CAP + m0) * HID + n0;
    int rr = tid >> 4;
    int cc = (tid & 15) * 8;
    #pragma unroll
    for (int j = 0; j < 8; ++j) {
        int row = rr + 16 * j;
        bf16x8 v = *(const bf16x8*)&smem[row * LDB_B + cc];
        *(bf16x8*)(Op + (size_t)row * HID + cc) = v;
    }
}

// --------------------------------------------------------------- combine ----
__global__ __launch_bounds__(256) void combine_kernel(const float* __restrict__ aff,
                                                      const int* __restrict__ eidx,
                                                      const int* __restrict__ perm,
                                                      const unsigned short* __restrict__ pout,
                                                      float* __restrict__ out) {
    int t = blockIdx.x;
    int e0 = eidx[t * 2], e1 = eidx[t * 2 + 1];
    int p0 = perm[t * 2], p1 = perm[t * 2 + 1];
    bool k0 = p0 > 0, k1 = p1 > 0;
    float a0 = aff[t * NE + e0], a1 = aff[t * NE + e1];
    // denom counts each distinct kept expert once (duplicate top-k -> once)
    float denom = (k0 ? fabsf(a0) : 0.f) + ((e1 != e0 && k1) ? fabsf(a1) : 0.f);
    denom = fmaxf(denom, 1e-12f);
    float w0 = k0 ? a0 / denom : 0.f;
    float w1 = k1 ? a1 / denom : 0.f;
    int s0 = k0 ? p0 - 1 : 0;
    int s1 = k1 ? p1 - 1 : 0;
    int h = threadIdx.x * 4;
    ushort4 v0 = *(const ushort4*)(pout + (size_t)s0 * HID + h);
    ushort4 v1 = *(const ushort4*)(pout + (size_t)s1 * HID + h);
    float4 o;
    o.x = w0 * bf2f(v0.x) + w1 * bf2f(v1.x);
    o.y = w0 * bf2f(v0.y) + w1 * bf2f(v1.y);
    o.z = w0 * bf2f(v0.z) + w1 * bf2f(v1.z);
    o.w = w0 * bf2f(v0.w) + w1 * bf2f(v1.w);
    *(float4*)(out + (size_t)t * HID + h) = o;
}

// ----------------------------------------------------------------- launch ---
extern "C" void kernel_launch(void* const* d_in, const int* in_sizes, int n_in,
                              void* d_out, int out_size, void* d_ws, size_t ws_size,
                              hipStream_t stream) {
    const float* hs   = (const float*)d_in[0];   // (T, HID)
    const float* aff  = (const float*)d_in[1];   // (T, NE)
    const float* gw   = (const float*)d_in[2];   // (NE, HID, INTER)
    const float* uw   = (const float*)d_in[3];   // (NE, HID, INTER)
    const float* dw   = (const float*)d_in[4];   // (NE, INTER, HID)
    const int*   eidx = (const int*)d_in[5];     // (T, TOPK)
    float* out = (float*)d_out;

    char* ws = (char*)d_ws;
    unsigned short* WgT    = (unsigned short*)(ws);
    unsigned short* WuT    = (unsigned short*)(ws + ((size_t)64  << 20));
    unsigned short* WdT    = (unsigned short*)(ws + ((size_t)128 << 20));
    unsigned short* Xe     = (unsigned short*)(ws + ((size_t)192 << 20));
    unsigned short* interB = (unsigned short*)(ws + ((size_t)224 << 20));
    unsigned short* pout   = (unsigned short*)(ws + ((size_t)352 << 20));
    int*            perm   = (int*)           (ws + ((size_t)416 << 20));
    int*            assign = perm + (T_TOK * TOPK);

    route_kernel<<<1, 512, 0, stream>>>(eidx, perm, assign);
    transpose_cvt<<<dim3(INTER / 64, HID / 64, NE), 256, 0, stream>>>(uw, WuT, HID, INTER);
    transpose_cvt<<<dim3(INTER / 64, HID / 64, NE), 256, 0, stream>>>(gw, WgT, HID, INTER);
    gather_cvt<<<EC, 256, 0, stream>>>(hs, assign, Xe);
    gateup_gemm<<<dim3(CAP / 128, INTER / 64, NE), 256, 0, stream>>>(Xe, WgT, WuT, interB);
    transpose_cvt<<<dim3(HID / 64, INTER / 64, NE), 256, 0, stream>>>(dw, WdT, INTER, HID);
    down_gemm<<<dim3(CAP / 128, HID / 128, NE), 256, 0, stream>>>(interB, WdT, pout);
    combine_kernel<<<T_TOK, 256, 0, stream>>>(aff, eidx, perm, pout, out);
}